// Round 3
// baseline (473.103 us; speedup 1.0000x reference)
//
#include <hip/hip_runtime.h>
#include <hip/hip_bf16.h>

// Problem constants (from reference)
#define M_TOTAL 65536   // N_IDS
#define ND      128     // N_DOCS
#define FDIM    220     // FEATURE_DIM
#define HID     768     // HIDDEN
#define G8      28      // groups of 8 cols per row (27 full + 1 tail of 4)
#define BSTRIDE 232     // LDS row stride (bf16) for W tile: 464B rows ->
                        // 16B-aligned, 2-way bank conflict (free per m136)

using bf16_t = __hip_bfloat16;
using bf16x8 = __attribute__((ext_vector_type(8))) short;  // 8 bf16 = 4 VGPRs
using f32x4  = __attribute__((ext_vector_type(4))) float;  // MFMA acc

struct __align__(16) bf16v8 { bf16_t v[8]; };

__device__ __forceinline__ float slog(float x) {
  return copysignf(log1pf(fabsf(x)), x);  // log(|x|+1) * sign(x)
}

// ---------------------------------------------------------------------------
// Kernel 1: gather rows of feature_table by (qid,did), apply signed log1p,
// write fp32 feature_batch (output 2) ONLY. 8 floats per thread.
// ---------------------------------------------------------------------------
__global__ __launch_bounds__(256) void gather_transform_kernel(
    const int2* __restrict__ ids, const float* __restrict__ table,
    float* __restrict__ fb)
{
  const int j   = blockIdx.x * 256 + threadIdx.x;  // grid is exact: 65536*28
  const int row = j / G8;
  const int g   = j % G8;

  const int2 p = ids[row];  // (qid, did), 8B load
  const float* src = table + ((size_t)p.x * ND + p.y) * FDIM + g * 8;
  float*       dst = fb + (size_t)row * FDIM + g * 8;

  const float4 f0 = *(const float4*)src;  // cols g*8..g*8+3 (216..219 for g=27)
  float4 y0;
  y0.x = slog(f0.x); y0.y = slog(f0.y); y0.z = slog(f0.z); y0.w = slog(f0.w);
  *(float4*)dst = y0;

  if (g < 27) {  // cols g*8+4..g*8+7 (g=27 has no second half: row ends at 220)
    const float4 f1 = *(const float4*)(src + 4);
    float4 y1;
    y1.x = slog(f1.x); y1.y = slog(f1.y); y1.z = slog(f1.z); y1.w = slog(f1.w);
    *(float4*)(dst + 4) = y1;
  }
}

// ---------------------------------------------------------------------------
// Kernel 2: out = relu(fb @ W^T + bias), fb=[M,220] fp32 (read back from
// d_out, L2/L3-hot), W=[768,220] fp32. W tile (128x224, fp32->bf16) staged
// ONCE into LDS; barrier-free K-loop; A fragments loaded fp32 from global and
// converted to bf16 inline. 7 unrolled K-steps, 112 MFMA/wave, 16 acc chains.
// ---------------------------------------------------------------------------
__global__ __launch_bounds__(256, 2) void gemm_bias_relu_kernel(
    const float* __restrict__ A, const float* __restrict__ W,
    const float* __restrict__ bias, float* __restrict__ out)
{
  __shared__ bf16_t Bs[128 * BSTRIDE];  // 59392 B -> 2 blocks/CU

  const int tid = threadIdx.x;
  const int bn  = blockIdx.x;  // 0..5   (N tiles, fastest -> A-tile L2 reuse)
  const int bm  = blockIdx.y;  // 0..511 (M tiles)

  // ---- stage W tile: 128 rows x 224 cols (fp32 -> bf16, pad cols 220..223=0)
#pragma unroll
  for (int it = 0; it < 14; ++it) {
    const int jj  = it * 256 + tid;
    const int row = jj / 28;
    const int g   = jj % 28;
    const float* src = W + (size_t)(bn * 128 + row) * FDIM + g * 8;
    const float4 f0 = *(const float4*)src;
    float4 f1;
    if (g < 27) {
      f1 = *(const float4*)(src + 4);
    } else {
      f1.x = 0.f; f1.y = 0.f; f1.z = 0.f; f1.w = 0.f;
    }
    bf16v8 h;
    h.v[0] = __float2bfloat16(f0.x); h.v[1] = __float2bfloat16(f0.y);
    h.v[2] = __float2bfloat16(f0.z); h.v[3] = __float2bfloat16(f0.w);
    h.v[4] = __float2bfloat16(f1.x); h.v[5] = __float2bfloat16(f1.y);
    h.v[6] = __float2bfloat16(f1.z); h.v[7] = __float2bfloat16(f1.w);
    *(bf16v8*)(Bs + row * BSTRIDE + g * 8) = h;
  }
  __syncthreads();  // the ONLY barrier

  const int wave = tid >> 6;
  const int lane = tid & 63;
  const int wm   = wave & 1;
  const int wn   = wave >> 1;
  const int l15  = lane & 15;
  const int q    = lane >> 4;

  f32x4 acc[4][4];
#pragma unroll
  for (int i = 0; i < 4; ++i)
#pragma unroll
    for (int j = 0; j < 4; ++j) acc[i][j] = (f32x4){0.f, 0.f, 0.f, 0.f};

  // A fragment: row = bm*128 + wm*64 + mi*16 + l15, cols kb*32 + q*8 .. +7
  const float*  Abase  = A + (size_t)(bm * 128 + wm * 64 + l15) * FDIM + q * 8;
  const bf16_t* BsBase = Bs + (wn * 64 + l15) * BSTRIDE + q * 8;

#pragma unroll
  for (int kb = 0; kb < 7; ++kb) {
    bf16x8 af[4], bg[4];
#pragma unroll
    for (int mi = 0; mi < 4; ++mi) {
      const float* ap = Abase + (size_t)mi * 16 * FDIM + kb * 32;
      const float4 f0 = *(const float4*)ap;  // cols 216..219 valid even at tail
      float4 f1;
      if (kb == 6 && q == 3) {               // cols 220..223 don't exist: pad 0
        f1.x = 0.f; f1.y = 0.f; f1.z = 0.f; f1.w = 0.f;
      } else {
        f1 = *(const float4*)(ap + 4);
      }
      bf16v8 h;
      h.v[0] = __float2bfloat16(f0.x); h.v[1] = __float2bfloat16(f0.y);
      h.v[2] = __float2bfloat16(f0.z); h.v[3] = __float2bfloat16(f0.w);
      h.v[4] = __float2bfloat16(f1.x); h.v[5] = __float2bfloat16(f1.y);
      h.v[6] = __float2bfloat16(f1.z); h.v[7] = __float2bfloat16(f1.w);
      af[mi] = *(const bf16x8*)&h;
    }
#pragma unroll
    for (int ni = 0; ni < 4; ++ni)
      bg[ni] = *(const bf16x8*)(BsBase + ni * 16 * BSTRIDE + kb * 32);
#pragma unroll
    for (int mi = 0; mi < 4; ++mi)
#pragma unroll
      for (int ni = 0; ni < 4; ++ni)
        acc[mi][ni] = __builtin_amdgcn_mfma_f32_16x16x32_bf16(
            af[mi], bg[ni], acc[mi][ni], 0, 0, 0);
  }

  // Epilogue: C/D layout col = lane&15, row = (lane>>4)*4 + reg  [m89-verified]
  const int col0 = bn * 128 + wn * 64 + l15;
  const int row0 = bm * 128 + wm * 64 + q * 4;
#pragma unroll
  for (int ni = 0; ni < 4; ++ni) {
    const int n    = col0 + ni * 16;
    const float bv = bias[n];
#pragma unroll
    for (int mi = 0; mi < 4; ++mi) {
#pragma unroll
      for (int r = 0; r < 4; ++r) {
        float v = acc[mi][ni][r] + bv;
        out[(size_t)(row0 + mi * 16 + r) * HID + n] = v > 0.f ? v : 0.f;
      }
    }
  }
}

extern "C" void kernel_launch(void* const* d_in, const int* in_sizes, int n_in,
                              void* d_out, int out_size, void* d_ws, size_t ws_size,
                              hipStream_t stream) {
  (void)in_sizes; (void)n_in; (void)out_size; (void)d_ws; (void)ws_size;

  const int2*  ids   = (const int2*)d_in[0];
  const float* table = (const float*)d_in[1];
  const float* W     = (const float*)d_in[2];
  const float* bias  = (const float*)d_in[3];

  float* out_embeds = (float*)d_out;                          // 65536*768 fp32
  float* fb_f32     = (float*)d_out + (size_t)M_TOTAL * HID;  // 65536*220 fp32

  gather_transform_kernel<<<(M_TOTAL * G8) / 256, 256, 0, stream>>>(
      ids, table, fb_f32);

  dim3 grid(HID / 128, M_TOTAL / 128);  // (6, 512), bn fastest for A reuse
  gemm_bias_relu_kernel<<<grid, 256, 0, stream>>>(fb_f32, W, bias, out_embeds);
}

// Round 4
// 423.132 us; speedup vs baseline: 1.1181x; 1.1181x over previous
//
#include <hip/hip_runtime.h>
#include <hip/hip_bf16.h>

// Problem constants (from reference)
#define M_TOTAL 65536   // N_IDS
#define ND      128     // N_DOCS
#define FDIM    220     // FEATURE_DIM
#define KPAD    224     // FDIM padded to multiple of 32 for MFMA
#define HID     768     // HIDDEN
#define G8      28      // groups of 8 cols per 224-col padded row
#define BSTRIDE 232     // LDS row stride (bf16): 464 B rows -> 16B-aligned,
                        // 2-way bank conflict on frag reads (free per m136)

using bf16_t = __hip_bfloat16;
using bf16x8 = __attribute__((ext_vector_type(8))) short;  // 8 bf16 = 4 VGPRs
using f32x4  = __attribute__((ext_vector_type(4))) float;  // MFMA acc

struct __align__(16) bf16v8 { bf16_t v[8]; };

__device__ __forceinline__ float slog(float x) {
  return copysignf(log1pf(fabsf(x)), x);  // log(|x|+1) * sign(x)
}

__device__ __forceinline__ float4 slog4(float4 f) {
  float4 y;
  y.x = slog(f.x); y.y = slog(f.y); y.z = slog(f.z); y.w = slog(f.w);
  return y;
}

__device__ __forceinline__ bf16v8 pack8(float4 a, float4 b) {
  bf16v8 h;
  h.v[0] = __float2bfloat16(a.x); h.v[1] = __float2bfloat16(a.y);
  h.v[2] = __float2bfloat16(a.z); h.v[3] = __float2bfloat16(a.w);
  h.v[4] = __float2bfloat16(b.x); h.v[5] = __float2bfloat16(b.y);
  h.v[6] = __float2bfloat16(b.z); h.v[7] = __float2bfloat16(b.w);
  return h;
}

// ---------------------------------------------------------------------------
// Kernel 1 (tiny): W [768x220] fp32 -> Wb [768x224] bf16 in d_ws. 84 blocks.
// ---------------------------------------------------------------------------
__global__ __launch_bounds__(256) void convert_w_kernel(
    const float* __restrict__ W, bf16_t* __restrict__ Wb)
{
  const int j   = blockIdx.x * 256 + threadIdx.x;  // exact: 768*28 = 84*256
  const int row = j / G8;
  const int g   = j % G8;

  const float* src = W + (size_t)row * FDIM + g * 8;
  const float4 f0 = *(const float4*)src;          // cols 216..219 ok for g=27
  float4 f1;
  if (g < 27) f1 = *(const float4*)(src + 4);
  else        { f1.x = 0.f; f1.y = 0.f; f1.z = 0.f; f1.w = 0.f; }  // pad 220..223
  *(bf16v8*)(Wb + (size_t)row * KPAD + g * 8) = pack8(f0, f1);
}

// ---------------------------------------------------------------------------
// Kernel 2 (fused): per 128-row M-tile —
//   stage: gather table rows by (qid,did), slog, write fb_f32 (output 2),
//          convert bf16 -> LDS A-tile (stride 232). ONE barrier.
//   compute: load all 7x4 A-fragments to registers once; loop bn=0..5 over
//          128-col N-tiles reading bf16 Wb from global (L2-resident 344 KB);
//          112 MFMA per wave per N-tile, 16 independent acc chains;
//          epilogue bias+relu+store per tile.
// No inter-kernel A traffic, no per-K barriers, zero HBM overfetch on A.
// ---------------------------------------------------------------------------
__global__ __launch_bounds__(256, 2) void fused_gather_gemm_kernel(
    const int2* __restrict__ ids, const float* __restrict__ table,
    const bf16_t* __restrict__ Wb, const float* __restrict__ bias,
    float* __restrict__ out, float* __restrict__ fb)
{
  __shared__ bf16_t As[128 * BSTRIDE];  // 59392 B -> 2 blocks/CU

  const int tid = threadIdx.x;
  const int bm  = blockIdx.x;  // 0..511

  // ---- stage: 128 rows x 28 groups = 3584 tasks = 14 iters x 256 threads
#pragma unroll
  for (int it = 0; it < 14; ++it) {
    const int jj   = it * 256 + tid;
    const int row  = jj / G8;
    const int g    = jj % G8;
    const int grow = bm * 128 + row;
    const int2 p   = ids[grow];
    const float* src = table + ((size_t)p.x * ND + p.y) * FDIM + g * 8;
    float*       dst = fb + (size_t)grow * FDIM + g * 8;

    const float4 y0 = slog4(*(const float4*)src);
    *(float4*)dst = y0;
    float4 y1;
    if (g < 27) {
      y1 = slog4(*(const float4*)(src + 4));
      *(float4*)(dst + 4) = y1;
    } else {
      y1.x = 0.f; y1.y = 0.f; y1.z = 0.f; y1.w = 0.f;  // pad cols 220..223
    }
    *(bf16v8*)(As + row * BSTRIDE + g * 8) = pack8(y0, y1);
  }
  __syncthreads();  // the ONLY barrier

  const int wave = tid >> 6;
  const int lane = tid & 63;
  const int wm   = wave & 1;
  const int wn   = wave >> 1;
  const int l15  = lane & 15;
  const int q    = lane >> 4;

  // ---- A fragments: row = wm*64 + mi*16 + l15, col = kb*32 + q*8 (held in regs)
  bf16x8 af[7][4];
#pragma unroll
  for (int kb = 0; kb < 7; ++kb)
#pragma unroll
    for (int mi = 0; mi < 4; ++mi)
      af[kb][mi] =
          *(const bf16x8*)(As + (wm * 64 + mi * 16 + l15) * BSTRIDE + kb * 32 + q * 8);

  // ---- N-loop over 6 column tiles
  for (int bn = 0; bn < 6; ++bn) {
    f32x4 acc[4][4];
#pragma unroll
    for (int i = 0; i < 4; ++i)
#pragma unroll
      for (int j = 0; j < 4; ++j) acc[i][j] = (f32x4){0.f, 0.f, 0.f, 0.f};

    // B fragment: row = bn*128 + wn*64 + ni*16 + l15, col = kb*32 + q*8
    const bf16_t* Wbase = Wb + (size_t)(bn * 128 + wn * 64 + l15) * KPAD + q * 8;

#pragma unroll
    for (int kb = 0; kb < 7; ++kb) {
      bf16x8 bg[4];
#pragma unroll
      for (int ni = 0; ni < 4; ++ni)
        bg[ni] = *(const bf16x8*)(Wbase + (size_t)ni * 16 * KPAD + kb * 32);
#pragma unroll
      for (int mi = 0; mi < 4; ++mi)
#pragma unroll
        for (int ni = 0; ni < 4; ++ni)
          acc[mi][ni] = __builtin_amdgcn_mfma_f32_16x16x32_bf16(
              af[kb][mi], bg[ni], acc[mi][ni], 0, 0, 0);
    }

    // epilogue: C/D layout col = lane&15, row = (lane>>4)*4 + reg [m89-verified]
    const int col0 = bn * 128 + wn * 64 + l15;
    const int row0 = bm * 128 + wm * 64 + q * 4;
#pragma unroll
    for (int ni = 0; ni < 4; ++ni) {
      const int n    = col0 + ni * 16;
      const float bv = bias[n];
#pragma unroll
      for (int mi = 0; mi < 4; ++mi) {
#pragma unroll
        for (int r = 0; r < 4; ++r) {
          float v = acc[mi][ni][r] + bv;
          out[(size_t)(row0 + mi * 16 + r) * HID + n] = v > 0.f ? v : 0.f;
        }
      }
    }
  }
}

extern "C" void kernel_launch(void* const* d_in, const int* in_sizes, int n_in,
                              void* d_out, int out_size, void* d_ws, size_t ws_size,
                              hipStream_t stream) {
  (void)in_sizes; (void)n_in; (void)out_size; (void)ws_size;

  const int2*  ids   = (const int2*)d_in[0];
  const float* table = (const float*)d_in[1];
  const float* W     = (const float*)d_in[2];
  const float* bias  = (const float*)d_in[3];

  float* out_embeds = (float*)d_out;                          // 65536*768 fp32
  float* fb_f32     = (float*)d_out + (size_t)M_TOTAL * HID;  // 65536*220 fp32

  bf16_t* Wb = (bf16_t*)d_ws;  // 768*224 bf16 = 344 KB

  convert_w_kernel<<<(HID * G8) / 256, 256, 0, stream>>>(W, Wb);

  fused_gather_gemm_kernel<<<M_TOTAL / 128, 256, 0, stream>>>(
      ids, table, Wb, bias, out_embeds, fb_f32);
}